// Round 8
// baseline (250.065 us; speedup 1.0000x reference)
//
#include <hip/hip_runtime.h>

// B=64, S=512, D=768 fp32.
// out = concat( hidden[:,0,:] (64*768), segment-mean by sent_id (64*20*768) )
//
// R8: natural-order streaming reads (no sorted scatter — testing the theory
// that scattered 768B-1KB granules cap reads at ~2.2 TB/s while sequential
// streams hit 6+). Block = (b, dc in 4, sc in 4) = 1024 blocks x 256 thr.
// Each wave streams 32 consecutive rows of its 192-float column slice in
// memory order, double-buffered in batches of 8: issue batch t+1's 8 loads
// BEFORE batch t's ds_add_f32 atomics (program order!), so the 8-row ring
// survives even if atomics pin the scheduler (R6 lesson). sids packed 8/reg.
// Epilogue: global fp32 atomics into zeroed sent_reps; fin divides.

constexpr int B_  = 64;
constexpr int S_  = 512;
constexpr int D_  = 768;
constexpr int M1  = 21;         // sid in [0,20]
constexpr int MS  = 20;         // segments emitted
constexpr int CF  = 192;        // floats per column chunk (64 lanes x 3)
constexpr int NDC = 4;          // D / CF
constexpr int NSC = 4;          // S chunks
constexpr int SC  = S_ / NSC;   // 128 rows per chunk
constexpr int NT  = 256;        // threads per block = 4 waves
constexpr int NW  = 4;
constexpr int RPW = SC / NW;    // 32 rows per wave
constexpr int BAT = 8;          // rows per double-buffered batch
constexpr int NB  = RPW / BAT;  // 4 batches

constexpr int ZBLK = (B_ * MS * D_ / 4) / NT;   // 960 zero blocks
constexpr int DBLK = (B_ * D_ / 4) / NT;        // 48 doc_cls blocks

struct f3 { float x, y, z; };

__global__ __launch_bounds__(NT)
void prep_kernel(const float* __restrict__ hidden, float* __restrict__ out) {
    int blk = blockIdx.x, tid = threadIdx.x;
    if (blk < ZBLK) {
        float4 z = {0.f, 0.f, 0.f, 0.f};
        ((float4*)(out + (size_t)B_ * D_))[blk * NT + tid] = z;
    } else {
        int f  = (blk - ZBLK) * NT + tid;       // float4 index into doc_cls
        int b  = f / (D_ / 4);
        int c4 = f - b * (D_ / 4);
        ((float4*)out)[f] = ((const float4*)hidden)[(size_t)b * S_ * (D_ / 4) + c4];
    }
}

__global__ __launch_bounds__(NT, 4)
void aspire_main(const float* __restrict__ hidden,
                 const int* __restrict__ sent_ids,
                 float* __restrict__ out) {
    __shared__ float acc[M1 * CF];   // 16128 B
    __shared__ int   sids_c[SC];

    const int b    = blockIdx.x;
    const int dc   = blockIdx.y;
    const int sc   = blockIdx.z;
    const int tid  = threadIdx.x;
    const int lane = tid & 63;
    const int w    = tid >> 6;       // 0..3

    for (int i = tid; i < M1 * CF; i += NT) acc[i] = 0.0f;
    if (tid < SC) sids_c[tid] = sent_ids[b * S_ + sc * SC + tid];
    __syncthreads();

    // pack this wave's 32 sids (natural order) into 8 VGPRs
    const int r0 = w * RPW;
    unsigned pk[RPW / 4];
    #pragma unroll
    for (int q = 0; q < RPW / 4; ++q) {
        pk[q] = (unsigned)sids_c[r0 + 4*q]
              | ((unsigned)sids_c[r0 + 4*q + 1] << 8)
              | ((unsigned)sids_c[r0 + 4*q + 2] << 16)
              | ((unsigned)sids_c[r0 + 4*q + 3] << 24);
    }

    // wave streams rows [r0, r0+32) of this chunk, in memory order
    const float* hb = hidden + ((size_t)b * S_ + sc * SC + r0) * D_ + dc * CF + 3 * lane;

    f3 buf[2][BAT];
    #pragma unroll
    for (int j = 0; j < BAT; ++j)
        buf[0][j] = *(const f3*)(hb + (size_t)j * D_);

    #pragma unroll
    for (int t = 0; t < NB; ++t) {
        // issue next batch's 8 loads FIRST (before any atomic in program order)
        if (t + 1 < NB) {
            #pragma unroll
            for (int j = 0; j < BAT; ++j)
                buf[(t + 1) & 1][j] = *(const f3*)(hb + (size_t)((t + 1) * BAT + j) * D_);
        }
        // consume batch t: fire-and-forget ds_add_f32 (2 lanes/bank = free)
        #pragma unroll
        for (int j = 0; j < BAT; ++j) {
            int r   = t * BAT + j;
            int sid = (pk[r >> 2] >> ((r & 3) * 8)) & 0xff;
            float* a = &acc[sid * CF + 3 * lane];
            f3 v = buf[t & 1][j];
            unsafeAtomicAdd(a + 0, v.x);
            unsafeAtomicAdd(a + 1, v.y);
            unsafeAtomicAdd(a + 2, v.z);
        }
    }
    __syncthreads();

    // flush partials: native global fp32 atomics into zeroed sent_reps
    float* srep = out + (size_t)B_ * D_;
    for (int f = tid; f < MS * CF; f += NT) {
        int seg = f / CF;
        int col = f - seg * CF;
        unsafeAtomicAdd(&srep[((size_t)b * MS + seg) * D_ + dc * CF + col],
                        acc[seg * CF + col]);
    }
}

__global__ __launch_bounds__(NT)
void aspire_fin(const int* __restrict__ sent_ids, float* __restrict__ out) {
    __shared__ int cnt[M1];
    const int b   = blockIdx.x;
    const int tid = threadIdx.x;
    if (tid < M1) cnt[tid] = 0;
    __syncthreads();
    for (int i = tid; i < S_; i += NT)
        atomicAdd(&cnt[sent_ids[b * S_ + i]], 1);
    __syncthreads();

    float4* srep = (float4*)(out + (size_t)B_ * D_ + (size_t)b * MS * D_);
    for (int f4 = tid; f4 < MS * D_ / 4; f4 += NT) {
        int seg = (f4 * 4) / D_;
        float ct = (float)cnt[seg];
        ct = ct < 1.0f ? 1.0f : ct;
        float inv = 1.0f / ct;
        float4 v = srep[f4];
        v.x *= inv; v.y *= inv; v.z *= inv; v.w *= inv;
        srep[f4] = v;
    }
}

extern "C" void kernel_launch(void* const* d_in, const int* in_sizes, int n_in,
                              void* d_out, int out_size, void* d_ws, size_t ws_size,
                              hipStream_t stream) {
    const float* hidden   = (const float*)d_in[0];
    const int*   sent_ids = (const int*)d_in[1];
    float* out = (float*)d_out;

    prep_kernel<<<ZBLK + DBLK, NT, 0, stream>>>(hidden, out);

    dim3 grid(B_, NDC, NSC);                 // (64,4,4) = 1024 blocks
    aspire_main<<<grid, NT, 0, stream>>>(hidden, sent_ids, out);

    aspire_fin<<<B_, NT, 0, stream>>>(sent_ids, out);
}

// Round 9
// 211.796 us; speedup vs baseline: 1.1807x; 1.1807x over previous
//
#include <hip/hip_runtime.h>

// B=64, S=512, D=768 fp32.
// out = concat( hidden[:,0,:] (64*768), segment-mean by sent_id (64*20*768) )
//
// R9, single kernel. Grid (64 b, 4 dc) = 256 blocks (1/CU), 512 thr = 8 waves.
// Wave streams 64 consecutive rows of its 192-float column slice in natural
// memory order, double-buffered 8+8 (all-static indices -> ring survives).
// Per row: ZERO LDS ops, ZERO atomics — sid via v_readlane (wave-uniform
// SGPR) -> 20-way scalar switch into 20 register f3 accumulators (seg 20
// dropped via default). Evidence: per-row LDS atomics cost ~200cy/wave-op and
// serialize the loop (R1/R2/R6/R8 all ~133us); register acc runs ~45us (R3/R4/R7).
// Combine: plain LDS two-phase (no atomics), reduce, divide, plain stores.
// Block (b,dc) owns disjoint output -> no zeroing, no second kernel.

constexpr int B_  = 64;
constexpr int S_  = 512;
constexpr int D_  = 768;
constexpr int M1  = 21;        // sid in [0,20]
constexpr int MS  = 20;        // segments emitted
constexpr int CF  = 192;       // floats per column chunk (64 lanes x 3)
constexpr int NDC = 4;         // D / CF
constexpr int NW  = 8;         // waves per block
constexpr int NT  = 64 * NW;   // 512 threads
constexpr int RPW = S_ / NW;   // 64 rows per wave

struct f3 { float x, y, z; };

#define ACASE(K) case K: ax[K] += v.x; ay[K] += v.y; az[K] += v.z; break;

#define LOAD8(BUF, RL) { _Pragma("unroll") \
    for (int j = 0; j < 8; ++j) \
        BUF[j] = *(const f3*)(hb + (size_t)(r0 + (RL) + j) * D_); }

#define CONS8(BUF, RL) { _Pragma("unroll") \
    for (int j = 0; j < 8; ++j) { \
        int sid = __builtin_amdgcn_readlane(vsids, (unsigned)((RL) + j)); \
        f3 v = BUF[j]; \
        switch (sid) { \
            ACASE(0)  ACASE(1)  ACASE(2)  ACASE(3)  ACASE(4) \
            ACASE(5)  ACASE(6)  ACASE(7)  ACASE(8)  ACASE(9) \
            ACASE(10) ACASE(11) ACASE(12) ACASE(13) ACASE(14) \
            ACASE(15) ACASE(16) ACASE(17) ACASE(18) ACASE(19) \
            default: break; /* seg 20 dropped */ \
        } } }

__global__ __launch_bounds__(NT, 2)
void aspire_fused(const float* __restrict__ hidden,
                  const int* __restrict__ sent_ids,
                  float* __restrict__ out) {
    __shared__ float red[4][MS * CF];   // 61440 B (plain, no atomics)
    __shared__ int   sids_c[S_];        // 2048 B
    __shared__ int   cnt[M1];

    const int b    = blockIdx.x;
    const int dc   = blockIdx.y;
    const int tid  = threadIdx.x;
    const int lane = tid & 63;
    const int w    = tid >> 6;          // 0..7

    if (tid < M1) cnt[tid] = 0;
    __syncthreads();
    {
        int sv = sent_ids[b * S_ + tid];     // NT == S_, one each
        sids_c[tid] = sv;
        atomicAdd(&cnt[sv], 1);              // tiny int histogram (8 wave-ops)
    }
    if (tid < CF) {                          // doc_cls_reps = hidden[:,0,:]
        out[b * D_ + dc * CF + tid] = hidden[(size_t)b * S_ * D_ + dc * CF + tid];
    }
    __syncthreads();

    // ---- hot loop: natural-order stream, register accumulation ----
    const int r0 = w * RPW;                  // wave's first row
    const unsigned vsids = (unsigned)sids_c[r0 + lane];  // lane L holds sid(row r0+L)
    const float* hb = hidden + (size_t)b * S_ * D_ + dc * CF + 3 * lane;

    float ax[MS], ay[MS], az[MS];
    #pragma unroll
    for (int k = 0; k < MS; ++k) { ax[k] = 0.f; ay[k] = 0.f; az[k] = 0.f; }

    f3 bA[8], bB[8];
    LOAD8(bA, 0)

    int rl = 0;
    #pragma unroll 1
    for (int t = 0; t < 4; ++t) {            // 16 rows/iter, 64 total
        LOAD8(bB, rl + 8)                    // loads first (straight-line)
        CONS8(bA, rl)                        // then branchy consume
        if (t < 3) LOAD8(bA, rl + 16)
        CONS8(bB, rl + 8)
        rl += 16;
    }

    // ---- two-phase plain-LDS combine (8 waves -> 4 slices -> sum) ----
    if (w < 4) {
        #pragma unroll
        for (int k = 0; k < MS; ++k) {
            float* rp = &red[w][k * CF + 3 * lane];   // stride 3: 2 lanes/bank
            rp[0] = ax[k]; rp[1] = ay[k]; rp[2] = az[k];
        }
    }
    __syncthreads();
    if (w >= 4) {
        #pragma unroll
        for (int k = 0; k < MS; ++k) {
            float* rp = &red[w - 4][k * CF + 3 * lane];
            rp[0] += ax[k]; rp[1] += ay[k]; rp[2] += az[k];
        }
    }
    __syncthreads();

    // ---- reduce 4 slices, divide, plain store (block owns this slice) ----
    float* srep = out + (size_t)B_ * D_;
    for (int f = tid; f < MS * CF; f += NT) {
        float s = red[0][f] + red[1][f] + red[2][f] + red[3][f];
        int seg = f / CF;
        int col = f - seg * CF;
        float ct = (float)cnt[seg];
        ct = ct < 1.0f ? 1.0f : ct;
        srep[((size_t)b * MS + seg) * D_ + dc * CF + col] = s / ct;
    }
}

extern "C" void kernel_launch(void* const* d_in, const int* in_sizes, int n_in,
                              void* d_out, int out_size, void* d_ws, size_t ws_size,
                              hipStream_t stream) {
    const float* hidden   = (const float*)d_in[0];
    const int*   sent_ids = (const int*)d_in[1];
    float* out = (float*)d_out;

    dim3 grid(B_, NDC);                      // 256 blocks = 1/CU
    aspire_fused<<<grid, NT, 0, stream>>>(hidden, sent_ids, out);
}